// Round 3
// baseline (357.604 us; speedup 1.0000x reference)
//
#include <hip/hip_runtime.h>
#include <hip/hip_bf16.h>
#include <math.h>

#define BATCH 64
#define TLEN 512
#define DIM 768
#define NLAB 50

typedef __attribute__((ext_vector_type(8))) short short8;   // 8 bf16 (4 VGPRs)
typedef __attribute__((ext_vector_type(4))) float f32x4;    // MFMA acc

__device__ __forceinline__ unsigned short f2bf(float f) {
    unsigned int u = __float_as_uint(f);
    return (unsigned short)((u + 0x7FFFu + ((u >> 16) & 1u)) >> 16);
}

// ---------------------------------------------------------------------------
// prep: W fp32 [768 x 50] -> Bt bf16 [64 cols][768 k] (transposed, zero-pad)
// ---------------------------------------------------------------------------
__global__ __launch_bounds__(256) void wprep_kernel(const float* __restrict__ W,
                                                    unsigned short* __restrict__ Bt) {
    int idx = blockIdx.x * 256 + threadIdx.x;
    if (idx < 64 * DIM) {
        int c = idx / DIM;
        int k = idx - c * DIM;
        float v = (c < NLAB) ? W[k * NLAB + c] : 0.f;
        Bt[idx] = f2bf(v);
    }
}

// ---------------------------------------------------------------------------
// GEMM: LDS-staged double-buffered bf16 MFMA.
// Block: 256 thr (4 waves), tile 64 rows x 64 cols, BK=64 (2 MFMA k-chunks).
// LDS layout [row][k] bf16 with row stride 72 shorts (144B, 16B-aligned,
// m vs m+8 same banks -> 2-way, free).
// ---------------------------------------------------------------------------
#define LDR 72

__global__ __launch_bounds__(256, 2) void gemm_kernel(
    const float* __restrict__ A,              // [32768 x 768] fp32
    const unsigned short* __restrict__ Bt,    // [64 x 768] bf16 (col-major W)
    const float* __restrict__ bias,
    float* __restrict__ out)                  // [32768 x 50]
{
    __shared__ short As[2][64 * LDR];
    __shared__ short Bs[2][64 * LDR];

    const int tid = threadIdx.x;
    const int wave = tid >> 6;
    const int lane = tid & 63;
    const int m = lane & 15;
    const int q = lane >> 4;
    const int row0 = blockIdx.x * 64;

    // staging indices
    const int ar = tid >> 4;            // A: row (over 4 its: +16 rows? no: u=tid+it*256)
    (void)ar;

    f32x4 acc0 = {0.f,0.f,0.f,0.f}, acc1 = {0.f,0.f,0.f,0.f};
    f32x4 acc2 = {0.f,0.f,0.f,0.f}, acc3 = {0.f,0.f,0.f,0.f};

    // ---- first stage (k0 = 0), direct ----
    {
#pragma unroll
        for (int it = 0; it < 4; ++it) {
            int u = tid + it * 256;            // float4 index, 1024 total
            int r = u >> 4;                    // 16 float4 per row
            int c = u & 15;
            const float4 v = *(const float4*)(A + (size_t)(row0 + r) * DIM + c * 4);
            short4 p;
            p.x = (short)f2bf(v.x); p.y = (short)f2bf(v.y);
            p.z = (short)f2bf(v.z); p.w = (short)f2bf(v.w);
            *(short4*)&As[0][r * LDR + c * 4] = p;
        }
#pragma unroll
        for (int it = 0; it < 2; ++it) {
            int u = tid + it * 256;            // 16B unit index, 512 total
            int col = u >> 3;
            int kk = (u & 7) * 8;
            const short8 bv = *(const short8*)(Bt + (size_t)col * DIM + kk);
            *(short8*)&Bs[0][col * LDR + kk] = bv;
        }
    }
    __syncthreads();

    int buf = 0;
    for (int k0 = 64; k0 < DIM; k0 += 64) {
        // 1) issue next-stage global loads into registers
        float4 av[4];
#pragma unroll
        for (int it = 0; it < 4; ++it) {
            int u = tid + it * 256;
            int r = u >> 4;
            int c = u & 15;
            av[it] = *(const float4*)(A + (size_t)(row0 + r) * DIM + k0 + c * 4);
        }
        short8 bv[2];
#pragma unroll
        for (int it = 0; it < 2; ++it) {
            int u = tid + it * 256;
            int col = u >> 3;
            int kk = (u & 7) * 8;
            bv[it] = *(const short8*)(Bt + (size_t)col * DIM + k0 + kk);
        }

        // 2) compute on current buffer
#pragma unroll
        for (int ch = 0; ch < 2; ++ch) {
            const short8 af = *(const short8*)&As[buf][(wave * 16 + m) * LDR + ch * 32 + q * 8];
            const short8 b0 = *(const short8*)&Bs[buf][(0 * 16 + m) * LDR + ch * 32 + q * 8];
            const short8 b1 = *(const short8*)&Bs[buf][(1 * 16 + m) * LDR + ch * 32 + q * 8];
            const short8 b2 = *(const short8*)&Bs[buf][(2 * 16 + m) * LDR + ch * 32 + q * 8];
            const short8 b3 = *(const short8*)&Bs[buf][(3 * 16 + m) * LDR + ch * 32 + q * 8];
            acc0 = __builtin_amdgcn_mfma_f32_16x16x32_bf16(af, b0, acc0, 0, 0, 0);
            acc1 = __builtin_amdgcn_mfma_f32_16x16x32_bf16(af, b1, acc1, 0, 0, 0);
            acc2 = __builtin_amdgcn_mfma_f32_16x16x32_bf16(af, b2, acc2, 0, 0, 0);
            acc3 = __builtin_amdgcn_mfma_f32_16x16x32_bf16(af, b3, acc3, 0, 0, 0);
        }

        // 3) convert + write next stage to other buffer
        const int nb = buf ^ 1;
#pragma unroll
        for (int it = 0; it < 4; ++it) {
            int u = tid + it * 256;
            int r = u >> 4;
            int c = u & 15;
            short4 p;
            p.x = (short)f2bf(av[it].x); p.y = (short)f2bf(av[it].y);
            p.z = (short)f2bf(av[it].z); p.w = (short)f2bf(av[it].w);
            *(short4*)&As[nb][r * LDR + c * 4] = p;
        }
#pragma unroll
        for (int it = 0; it < 2; ++it) {
            int u = tid + it * 256;
            int col = u >> 3;
            int kk = (u & 7) * 8;
            *(short8*)&Bs[nb][col * LDR + kk] = bv[it];
        }
        __syncthreads();
        buf = nb;
    }

    // final chunk
#pragma unroll
    for (int ch = 0; ch < 2; ++ch) {
        const short8 af = *(const short8*)&As[buf][(wave * 16 + m) * LDR + ch * 32 + q * 8];
        const short8 b0 = *(const short8*)&Bs[buf][(0 * 16 + m) * LDR + ch * 32 + q * 8];
        const short8 b1 = *(const short8*)&Bs[buf][(1 * 16 + m) * LDR + ch * 32 + q * 8];
        const short8 b2 = *(const short8*)&Bs[buf][(2 * 16 + m) * LDR + ch * 32 + q * 8];
        const short8 b3 = *(const short8*)&Bs[buf][(3 * 16 + m) * LDR + ch * 32 + q * 8];
        acc0 = __builtin_amdgcn_mfma_f32_16x16x32_bf16(af, b0, acc0, 0, 0, 0);
        acc1 = __builtin_amdgcn_mfma_f32_16x16x32_bf16(af, b1, acc1, 0, 0, 0);
        acc2 = __builtin_amdgcn_mfma_f32_16x16x32_bf16(af, b2, acc2, 0, 0, 0);
        acc3 = __builtin_amdgcn_mfma_f32_16x16x32_bf16(af, b3, acc3, 0, 0, 0);
    }

    // epilogue: row = row0 + wave*16 + q*4 + r, col = nt*16 + m
    const f32x4 av4[4] = {acc0, acc1, acc2, acc3};
#pragma unroll
    for (int nt = 0; nt < 4; ++nt) {
        const int col = nt * 16 + m;
        if (col < NLAB) {
            const float bvv = bias[col];
#pragma unroll
            for (int r = 0; r < 4; ++r) {
                const int row = row0 + wave * 16 + q * 4 + r;
                out[(size_t)row * NLAB + col] = av4[nt][r] + bvv;
            }
        }
    }
}

// ---------------------------------------------------------------------------
// CRF: one wave per batch, lane j owns label j.
//   e_j = exp(alpha_j - A); per step: s = dot(e, expT[:,j]) via LDS broadcast,
//   u = s * exp(em) * rcp(e0_prev), A += log(e0_prev).
// v3: double-buffered ea (1 barrier/step) + 4-deep emission prefetch ring
//     + exp computed one step early.
// ---------------------------------------------------------------------------
__device__ __forceinline__ float wave_sum(float v) {
#pragma unroll
    for (int off = 32; off > 0; off >>= 1) v += __shfl_xor(v, off, 64);
    return v;
}

__global__ __launch_bounds__(64) void crf_kernel(
    const float* __restrict__ logits,
    const int* __restrict__ labels,
    const void* __restrict__ maskp,
    const float* __restrict__ startT,
    const float* __restrict__ endT,
    const float* __restrict__ trans,
    float* __restrict__ llh) {
    const int b = blockIdx.x;
    const int lane = threadIdx.x;
    __shared__ __align__(16) float ea[2][64];

    // --- mask length (contiguous valid prefix) ---
    const int probe = ((const int*)maskp)[0];
    int len = 0;
    if (probe == 1) {
        const int* mk = (const int*)maskp + b * TLEN;
#pragma unroll
        for (int it = 0; it < 8; ++it)
            len += (int)__popcll(__ballot(mk[lane + it * 64] != 0));
    } else if (probe == 0x01010101) {
        const unsigned char* mk = (const unsigned char*)maskp + b * TLEN;
#pragma unroll
        for (int it = 0; it < 8; ++it)
            len += (int)__popcll(__ballot(mk[lane + it * 64] != 0));
    } else if (probe == 0x3F803F80) {
        const unsigned short* mk = (const unsigned short*)maskp + b * TLEN;
#pragma unroll
        for (int it = 0; it < 8; ++it)
            len += (int)__popcll(__ballot(mk[lane + it * 64] != 0));
    } else {
        const float* mk = (const float*)maskp + b * TLEN;
#pragma unroll
        for (int it = 0; it < 8; ++it)
            len += (int)__popcll(__ballot(mk[lane + it * 64] != 0.f));
    }

    const int j = lane;
    const int jc = (j < NLAB) ? j : (NLAB - 1);

    float et[52];
#pragma unroll
    for (int i = 0; i < 52; ++i) et[i] = 0.f;
    if (j < NLAB) {
        for (int i = 0; i < NLAB; ++i) et[i] = __expf(trans[i * NLAB + j]);
    }

    const float* em = logits + (size_t)b * TLEN * NLAB;

    float a0 = (j < NLAB) ? (startT[j] + em[j]) : 0.f;
    const float Abc = __shfl(a0, 0, 64);
    float e = (j < NLAB) ? __expf(a0 - Abc) : 0.f;
    float A = Abc;

    ea[0][lane] = e;

    // emission prefetch ring: em for t = 1..4 (len >= 256 always)
    float q0 = em[1 * NLAB + jc];
    float q1 = em[2 * NLAB + jc];
    float q2 = em[3 * NLAB + jc];
    float q3 = em[4 * NLAB + jc];
    float pcur = __expf(q0);   // p for t=1
    q0 = q1; q1 = q2; q2 = q3;

    __syncthreads();

    int buf = 0;
    for (int t = 1; t < len; ++t) {
        const float pnext = __expf(q0);                 // p for t+1 (off-chain)
        const int tl = t + 4;
        const int tf = (tl < len) ? tl : (len - 1);
        const float newem = em[tf * NLAB + jc];         // 4 steps ahead

        const float* eb = ea[buf];
        const float ea0 = eb[0];
        float sa = 0.f, sb = 0.f, sc = 0.f, sd = 0.f;
#pragma unroll
        for (int qq = 0; qq < 13; ++qq) {
            const float4 v = *(const float4*)&eb[qq * 4];
            sa = fmaf(v.x, et[qq * 4 + 0], sa);
            sb = fmaf(v.y, et[qq * 4 + 1], sb);
            sc = fmaf(v.z, et[qq * 4 + 2], sc);
            sd = fmaf(v.w, et[qq * 4 + 3], sd);
        }
        const float s = (sa + sb) + (sc + sd);
        const float r = __builtin_amdgcn_rcpf(ea0);
        const float u = s * (pcur * r);
        A += __logf(ea0);

        ea[buf ^ 1][lane] = u;
        __syncthreads();
        buf ^= 1;
        e = u;
        pcur = pnext;
        q0 = q1; q1 = q2; q2 = newem;
    }

    const float wv = (j < NLAB) ? (e * __expf(endT[j])) : 0.f;
    const float den = A + __logf(wave_sum(wv));

    // numerator: gold path (contiguous mask -> parallel over t)
    const int* tg = labels + b * TLEN;
    float num = 0.f;
#pragma unroll
    for (int it = 0; it < 8; ++it) {
        const int t = lane + it * 64;
        if (t < len) {
            const int tag = tg[t];
            num += em[t * NLAB + tag];
            if (t >= 1) num += trans[tg[t - 1] * NLAB + tag];
        }
    }
    num = wave_sum(num);
    if (lane == 0) {
        num += startT[tg[0]] + endT[tg[len - 1]];
        llh[b] = num - den;
    }
}

__global__ __launch_bounds__(64) void loss_kernel(const float* __restrict__ llh,
                                                  float* __restrict__ out0) {
    float v = llh[threadIdx.x];
    v = wave_sum(v);
    if (threadIdx.x == 0) out0[0] = -(v * (1.0f / BATCH));
}

extern "C" void kernel_launch(void* const* d_in, const int* in_sizes, int n_in,
                              void* d_out, int out_size, void* d_ws, size_t ws_size,
                              hipStream_t stream) {
    (void)in_sizes; (void)n_in; (void)out_size; (void)ws_size;
    const float* emb    = (const float*)d_in[0];
    const int*   labels = (const int*)d_in[1];
    const void*  mask   = d_in[2];
    const float* W      = (const float*)d_in[3];
    const float* bias   = (const float*)d_in[4];
    const float* startT = (const float*)d_in[5];
    const float* endT   = (const float*)d_in[6];
    const float* trans  = (const float*)d_in[7];

    float* out    = (float*)d_out;
    float* logits = out + 1;
    float* llh    = (float*)d_ws;
    unsigned short* Bt = (unsigned short*)((char*)d_ws + 512);  // 96 KiB bf16 W^T

    wprep_kernel<<<(64 * DIM + 255) / 256, 256, 0, stream>>>(W, Bt);
    gemm_kernel<<<(BATCH * TLEN) / 64, 256, 0, stream>>>(emb, Bt, bias, logits);
    crf_kernel<<<BATCH, 64, 0, stream>>>(logits, labels, mask, startT, endT, trans, llh);
    loss_kernel<<<1, 64, 0, stream>>>(llh, out);
}